// Round 3
// baseline (222.078 us; speedup 1.0000x reference)
//
#include <hip/hip_runtime.h>
#include <hip/hip_bf16.h>
#include <math.h>

// Problem constants (fixed by setup_inputs)
#define BATCH 4
#define NHEAD 8
#define HD 24          // head dim
#define CH 192         // total channels
#define HW 16384       // h*w
#define SPL 32         // kA hw-chunks of 512 (2x256 cols accumulated in regs)
#define SROW 640       // Sp row: [0,576) gram, [576,600) sqq, [600,624) sqk, pad 640

// ws layout (floats):
//   Sp:  [32 bh][32 sp][640]   off 0        (2.62 MB)
//   Mo:  ushort[4][192][192]   off OFF_MO   (288 KB)
//   cnt: uint[32]              off OFF_CNT  (zeroed via tiny memset each launch)
#define OFF_MO  (32 * SPL * SROW)
#define OFF_CNT (OFF_MO + (BATCH * CH * CH) / 2)

#define LSTR 132   // u32 per kA LDS row (128 data + 4 pad)

typedef __attribute__((ext_vector_type(8)))  short bf16x8;
typedef __attribute__((ext_vector_type(16))) float f32x16;

__device__ __forceinline__ unsigned short bf16rne(float x) {
    union { float f; unsigned u; } v; v.f = x;
    unsigned u = v.u;
    return (unsigned short)((u + 0x7FFFu + ((u >> 16) & 1u)) >> 16);
}

__device__ __forceinline__ unsigned pack2(float a, float b) {
    union { __hip_bfloat162 h; unsigned u; } c;
    c.h = __float22bfloat162_rn(float2{a, b});
    return c.u;
}

// ---------------------------------------------------------------------------
// Kernel A + fused finalizer. Per (bh, 512-col chunk): two 256-col sub-chunks,
// coalesced fp32 loads -> bf16 LDS tiles, MFMA Gram (32x32x16) accumulated in
// registers, one partial-row write. Then the LAST block of each bh (agent-
// scope acq_rel semaphore) performs the old kB inline: split-reduce, norms,
// softmax, proj_w fold -> Mo (bf16). grid (32 bh, 32 ch), block 256, 4/CU.
// ---------------------------------------------------------------------------
__global__ __launch_bounds__(256, 4) void kA(const float* __restrict__ q,
                                             const float* __restrict__ k,
                                             const float* __restrict__ scale,
                                             const float* __restrict__ w,
                                             float* __restrict__ ws,
                                             unsigned short* __restrict__ Mo,
                                             unsigned int* __restrict__ cnt) {
    __shared__ unsigned int tile[2][HD * LSTR];   // 25.3 KB (reused by finalizer)
    __shared__ int lastFlag;

    const int bh   = blockIdx.x;
    const int ch   = blockIdx.y;      // 0..31 -> cols [ch*512, ch*512+512)
    const int t    = threadIdx.x;
    const int lane = t & 63;
    const int wave = t >> 6;
    const int m    = lane & 31;
    const int hi   = lane >> 5;
    const int rowc = (m < HD) ? m : 0;   // clamp: garbage only hits discarded C

    f32x16 aQK = {}, aQQ = {}, aKK = {};

    #pragma unroll
    for (int half = 0; half < 2; ++half) {
        const float* qb = q + (size_t)bh * HD * HW + ch * 512 + half * 256;
        const float* kb = k + (size_t)bh * HD * HW + ch * 512 + half * 256;

        #pragma unroll
        for (int j = 0; j < 6; ++j) {
            const int idx = j * 256 + t;        // 0..1535
            const int row = idx >> 6;           // 0..23
            const int c64 = idx & 63;
            float4 qv = *(const float4*)(qb + (size_t)row * HW + c64 * 4);
            float4 kv = *(const float4*)(kb + (size_t)row * HW + c64 * 4);
            *(uint2*)&tile[0][row * LSTR + c64 * 2] =
                make_uint2(pack2(qv.x, qv.y), pack2(qv.z, qv.w));
            *(uint2*)&tile[1][row * LSTR + c64 * 2] =
                make_uint2(pack2(kv.x, kv.y), pack2(kv.z, kv.w));
        }
        __syncthreads();

        #pragma unroll
        for (int s = 0; s < 4; ++s) {
            const int off = (wave * 64 + s * 16) >> 1;
            bf16x8 aq = *(const bf16x8*)&tile[0][rowc * LSTR + off + hi * 4];
            bf16x8 bk = *(const bf16x8*)&tile[1][rowc * LSTR + off + hi * 4];
            aQK = __builtin_amdgcn_mfma_f32_32x32x16_bf16(aq, bk, aQK, 0, 0, 0);
            aQQ = __builtin_amdgcn_mfma_f32_32x32x16_bf16(aq, aq, aQQ, 0, 0, 0);
            aKK = __builtin_amdgcn_mfma_f32_32x32x16_bf16(bk, bk, aKK, 0, 0, 0);
        }
        __syncthreads();   // LDS reuse (next half's staging / reduce scatter)
    }

    float* red = (float*)tile;
    if (m < HD) {
        #pragma unroll
        for (int r = 0; r < 16; ++r) {
            const int i = (r & 3) + 8 * (r >> 2) + 4 * hi;
            if (i < HD) {
                red[wave * 624 + i * HD + m] = aQK[r];
                if (i == m) {
                    red[wave * 624 + 576 + i] = aQQ[r];
                    red[wave * 624 + 600 + i] = aKK[r];
                }
            }
        }
    }
    __syncthreads();

    float* Srow = ws + ((size_t)bh * SPL + ch) * SROW;
    for (int e = t; e < 624; e += 256)
        Srow[e] = red[e] + red[624 + e] + red[1248 + e] + red[1872 + e];

    // ---- tail-block semaphore: last producer for this bh finalizes it ----
    __syncthreads();   // all lanes' Srow stores issued before t0's release RMW
    if (t == 0) {
        unsigned int old = __hip_atomic_fetch_add(&cnt[bh], 1u,
                                                  __ATOMIC_ACQ_REL,
                                                  __HIP_MEMORY_SCOPE_AGENT);
        lastFlag = (old == SPL - 1);
    }
    __syncthreads();
    if (!lastFlag) return;

    // ---------------- finalizer (old kB), 256 threads, LDS reuse ----------
    // sf layout: [0,624) SA | [624,648) qinv | [648,672) kinv | [672,5280) wl
    float* sf = (float*)tile;
    const int b = bh >> 3;
    const int h = bh & 7;
    const float* base = ws + (size_t)bh * SPL * SROW;

    for (int idx = t; idx < CH * HD; idx += 256) {
        int o = idx / HD, dd = idx - o * HD;
        sf[672 + idx] = w[o * CH + h * HD + dd];
    }
    for (int e = t; e < 624; e += 256) {
        float s0 = 0.f, s1 = 0.f, s2 = 0.f, s3 = 0.f;
        #pragma unroll
        for (int sp = 0; sp < SPL; sp += 4) {
            s0 += base[(size_t)(sp + 0) * SROW + e];
            s1 += base[(size_t)(sp + 1) * SROW + e];
            s2 += base[(size_t)(sp + 2) * SROW + e];
            s3 += base[(size_t)(sp + 3) * SROW + e];
        }
        sf[e] = (s0 + s1) + (s2 + s3);
    }
    __syncthreads();

    if (t < 2 * HD) {
        float inv = 1.0f / fmaxf(sqrtf(sf[576 + t]), 1e-12f);
        sf[624 + t] = inv;                     // qinv at 624, kinv at 648
    }
    __syncthreads();

    const float sc = scale[h];
    for (int e = t; e < 576; e += 256)
        sf[e] = sf[e] * sf[624 + e / HD] * sf[648 + e % HD] * sc;
    __syncthreads();

    if (t < HD) {   // softmax along j for row t
        float mx = -1e30f;
        for (int j = 0; j < HD; ++j) mx = fmaxf(mx, sf[t * HD + j]);
        float sum = 0.f;
        for (int j = 0; j < HD; ++j) {
            float v = expf(sf[t * HD + j] - mx);
            sf[t * HD + j] = v;
            sum += v;
        }
        float r = 1.0f / sum;
        for (int j = 0; j < HD; ++j) sf[t * HD + j] *= r;
    }
    __syncthreads();

    // Mo[b][o][h*24+j] = (sum_i w[o,h*24+i] * attn[i][j]) * kinv[j]  (bf16)
    for (int idx = t; idx < CH * HD; idx += 256) {
        int o = idx / HD, j = idx - o * HD;
        float v = 0.f;
        #pragma unroll
        for (int i = 0; i < HD; ++i)
            v = fmaf(sf[672 + o * HD + i], sf[i * HD + j], v);
        Mo[(size_t)b * CH * CH + (size_t)o * CH + h * HD + j] = bf16rne(v * sf[648 + j]);
    }
}

// ---------------------------------------------------------------------------
// Kernel C: out[b][o][n] = sum_c Mo[b][o][c] * in2[b][c][n]  via mfma_32x32x16.
// Block tile O=192 x N=64. Single-shot staging: the ENTIRE 64n x 192c k-tile
// is loaded up-front with 12 float4 loads/thread (1 KB/wave segments, deep
// MLP), ONE barrier, then 36 back-to-back MFMAs. grid (256 nblk, 4 b),
// block 256, 4 blocks/CU.
// ---------------------------------------------------------------------------
#define KCN 64
#define BSTR3 100   // u32 per n-row: 96 data (192 ch as bf16 pairs) + 4 pad

__global__ __launch_bounds__(256, 4) void kC(const float* __restrict__ k,
                                             const unsigned short* __restrict__ Mo,
                                             float* __restrict__ out) {
    __shared__ unsigned int Bt[KCN * BSTR3];   // 25.6 KB

    const int t    = threadIdx.x;
    const int lane = t & 63;
    const int wave = t >> 6;
    const int n31  = lane & 31;
    const int hi   = lane >> 5;
    const int nt   = wave & 1;          // n-tile (x32)
    const int otb  = (wave >> 1) * 3;   // first o-tile (x32) of this wave

    const int nb = blockIdx.x * KCN;
    const int b  = blockIdx.y;

    const float* kb = k + (size_t)b * CH * HW;
    const unsigned short* Mob = Mo + (size_t)b * CH * CH;

    const int np4 = t & 15;   // n-quad: rows np4*4 .. +3
    const int cg4 = t >> 4;   // 0..15: channels cg4*4 .. +3 per 64-ch stage

    // Stage the whole 64 x 192 tile (fp32 -> bf16 pairs), one barrier.
    #pragma unroll
    for (int s = 0; s < 3; ++s) {
        float4 v[4];
        #pragma unroll
        for (int cc = 0; cc < 4; ++cc)
            v[cc] = *(const float4*)(kb + (size_t)(s * 64 + cg4 * 4 + cc) * HW + nb + np4 * 4);
        #pragma unroll
        for (int r = 0; r < 4; ++r) {
            float x0 = (&v[0].x)[r], x1 = (&v[1].x)[r];
            float x2 = (&v[2].x)[r], x3 = (&v[3].x)[r];
            *(uint2*)&Bt[(np4 * 4 + r) * BSTR3 + s * 32 + cg4 * 2] =
                make_uint2(pack2(x0, x1), pack2(x2, x3));
        }
    }
    __syncthreads();

    f32x16 acc[3] = {};
    #pragma unroll
    for (int kc = 0; kc < 12; ++kc) {
        bf16x8 Bf = *(const bf16x8*)&Bt[(nt * 32 + n31) * BSTR3 + kc * 8 + hi * 4];
        #pragma unroll
        for (int oi = 0; oi < 3; ++oi) {
            const unsigned short* ap =
                Mob + (size_t)((otb + oi) * 32 + n31) * CH + kc * 16 + hi * 8;
            bf16x8 Af = *(const bf16x8*)ap;
            acc[oi] = __builtin_amdgcn_mfma_f32_32x32x16_bf16(Af, Bf, acc[oi], 0, 0, 0);
        }
    }

    float* op = out + (size_t)b * CH * HW;
    const int n = nb + nt * 32 + n31;
    #pragma unroll
    for (int oi = 0; oi < 3; ++oi)
        #pragma unroll
        for (int r = 0; r < 16; ++r) {
            int o = (otb + oi) * 32 + (r & 3) + 8 * (r >> 2) + 4 * hi;
            op[(size_t)o * HW + n] = acc[oi][r];
        }
}

extern "C" void kernel_launch(void* const* d_in, const int* in_sizes, int n_in,
                              void* d_out, int out_size, void* d_ws, size_t ws_size,
                              hipStream_t stream) {
    const float* in1   = (const float*)d_in[0];
    const float* in2   = (const float*)d_in[1];
    const float* scale = (const float*)d_in[2];
    const float* projw = (const float*)d_in[3];
    float* ws  = (float*)d_ws;   // needs ~2.9 MB
    float* out = (float*)d_out;
    unsigned short* Mo = (unsigned short*)(ws + OFF_MO);
    unsigned int* cnt  = (unsigned int*)(ws + OFF_CNT);

    // ws is poisoned each iteration by the harness -> zero the 32 semaphores.
    hipMemsetAsync((void*)cnt, 0, 32 * sizeof(unsigned int), stream);
    kA<<<dim3(32, SPL), 256, 0, stream>>>(in1, in2, scale, projw, ws, Mo, cnt);
    kC<<<dim3(HW / KCN, BATCH), 256, 0, stream>>>(in2, Mo, out);
}

// Round 4
// 174.155 us; speedup vs baseline: 1.2752x; 1.2752x over previous
//
#include <hip/hip_runtime.h>
#include <hip/hip_bf16.h>
#include <math.h>

// Problem constants (fixed by setup_inputs)
#define BATCH 4
#define NHEAD 8
#define HD 24          // head dim
#define CH 192         // total channels
#define HW 16384       // h*w
#define SPL 32         // kA hw-chunks of 512 (2x256 cols accumulated in regs)
#define SROW 640       // Sp row: [0,576) gram, [576,600) sqq, [600,624) sqk, pad 640

// ws layout (floats):
//   Sp:  [32 bh][32 sp][640]   off 0        (2.62 MB)
//   Mo:  ushort[4][192][192]   off OFF_MO   (288 KB)
//   cnt: uint[32]              off OFF_CNT  (zeroed via tiny memset each launch)
#define OFF_MO  (32 * SPL * SROW)
#define OFF_CNT (OFF_MO + (BATCH * CH * CH) / 2)

#define LSTR 132   // u32 per kA LDS row (128 data + 4 pad)

typedef __attribute__((ext_vector_type(8)))  short bf16x8;
typedef __attribute__((ext_vector_type(16))) float f32x16;

__device__ __forceinline__ unsigned short bf16rne(float x) {
    union { float f; unsigned u; } v; v.f = x;
    unsigned u = v.u;
    return (unsigned short)((u + 0x7FFFu + ((u >> 16) & 1u)) >> 16);
}

__device__ __forceinline__ unsigned pack2(float a, float b) {
    union { __hip_bfloat162 h; unsigned u; } c;
    c.h = __float22bfloat162_rn(float2{a, b});
    return c.u;
}

// Agent-scope RELAXED accessors: compile to sc1 global ops committing at the
// L3 coherence point. NO fence instructions (no buffer_wbl2 / buffer_inv) —
// that per-block L2 flush was R3's 91us disaster.
__device__ __forceinline__ void st_agent(float* p, float v) {
    __hip_atomic_store(p, v, __ATOMIC_RELAXED, __HIP_MEMORY_SCOPE_AGENT);
}
__device__ __forceinline__ float ld_agent(const float* p) {
    return __hip_atomic_load(p, __ATOMIC_RELAXED, __HIP_MEMORY_SCOPE_AGENT);
}

// ---------------------------------------------------------------------------
// Kernel A + fenceless finalizer. Per (bh, 512-col chunk): two 256-col
// sub-chunks, coalesced fp32 loads -> bf16 LDS tiles, MFMA Gram (32x32x16)
// accumulated in registers, one partial-row write (sc1 stores). Per-wave
// vmcnt(0) drain + barrier, then t0 does a RELAXED agent RMW on cnt[bh].
// The block seeing old==SPL-1 knows all partials are at L3 and runs the old
// kB inline with sc1 loads. grid (32 bh, 32 ch), block 256, 4/CU.
// ---------------------------------------------------------------------------
__global__ __launch_bounds__(256, 4) void kA(const float* __restrict__ q,
                                             const float* __restrict__ k,
                                             const float* __restrict__ scale,
                                             const float* __restrict__ w,
                                             float* __restrict__ ws,
                                             unsigned short* __restrict__ Mo,
                                             unsigned int* __restrict__ cnt) {
    __shared__ unsigned int tile[2][HD * LSTR];   // 25.3 KB (reused by finalizer)
    __shared__ int lastFlag;

    const int bh   = blockIdx.x;
    const int ch   = blockIdx.y;      // 0..31 -> cols [ch*512, ch*512+512)
    const int t    = threadIdx.x;
    const int lane = t & 63;
    const int wave = t >> 6;
    const int m    = lane & 31;
    const int hi   = lane >> 5;
    const int rowc = (m < HD) ? m : 0;   // clamp: garbage only hits discarded C

    f32x16 aQK = {}, aQQ = {}, aKK = {};

    #pragma unroll
    for (int half = 0; half < 2; ++half) {
        const float* qb = q + (size_t)bh * HD * HW + ch * 512 + half * 256;
        const float* kb = k + (size_t)bh * HD * HW + ch * 512 + half * 256;

        #pragma unroll
        for (int j = 0; j < 6; ++j) {
            const int idx = j * 256 + t;        // 0..1535
            const int row = idx >> 6;           // 0..23
            const int c64 = idx & 63;
            float4 qv = *(const float4*)(qb + (size_t)row * HW + c64 * 4);
            float4 kv = *(const float4*)(kb + (size_t)row * HW + c64 * 4);
            *(uint2*)&tile[0][row * LSTR + c64 * 2] =
                make_uint2(pack2(qv.x, qv.y), pack2(qv.z, qv.w));
            *(uint2*)&tile[1][row * LSTR + c64 * 2] =
                make_uint2(pack2(kv.x, kv.y), pack2(kv.z, kv.w));
        }
        __syncthreads();

        #pragma unroll
        for (int s = 0; s < 4; ++s) {
            const int off = (wave * 64 + s * 16) >> 1;
            bf16x8 aq = *(const bf16x8*)&tile[0][rowc * LSTR + off + hi * 4];
            bf16x8 bk = *(const bf16x8*)&tile[1][rowc * LSTR + off + hi * 4];
            aQK = __builtin_amdgcn_mfma_f32_32x32x16_bf16(aq, bk, aQK, 0, 0, 0);
            aQQ = __builtin_amdgcn_mfma_f32_32x32x16_bf16(aq, aq, aQQ, 0, 0, 0);
            aKK = __builtin_amdgcn_mfma_f32_32x32x16_bf16(bk, bk, aKK, 0, 0, 0);
        }
        __syncthreads();   // LDS reuse (next half's staging / reduce scatter)
    }

    float* red = (float*)tile;
    if (m < HD) {
        #pragma unroll
        for (int r = 0; r < 16; ++r) {
            const int i = (r & 3) + 8 * (r >> 2) + 4 * hi;
            if (i < HD) {
                red[wave * 624 + i * HD + m] = aQK[r];
                if (i == m) {
                    red[wave * 624 + 576 + i] = aQQ[r];
                    red[wave * 624 + 600 + i] = aKK[r];
                }
            }
        }
    }
    __syncthreads();

    float* Srow = ws + ((size_t)bh * SPL + ch) * SROW;
    for (int e = t; e < 624; e += 256)
        st_agent(&Srow[e], red[e] + red[624 + e] + red[1248 + e] + red[1872 + e]);

    // Per-wave drain: sc1 stores retire vmcnt only when committed at the L3
    // coherence point, so after this they are agent-visible.
    asm volatile("s_waitcnt vmcnt(0)" ::: "memory");
    __syncthreads();   // all waves drained before t0's count increment

    if (t == 0) {
        unsigned int old = __hip_atomic_fetch_add(&cnt[bh], 1u,
                                                  __ATOMIC_RELAXED,
                                                  __HIP_MEMORY_SCOPE_AGENT);
        lastFlag = (old == SPL - 1);
    }
    __syncthreads();
    if (!lastFlag) return;

    // ---------------- finalizer (old kB), 256 threads, LDS reuse ----------
    // sf layout: [0,624) SA | [624,648) qinv | [648,672) kinv | [672,5280) wl
    float* sf = (float*)tile;
    const int b = bh >> 3;
    const int h = bh & 7;
    const float* base = ws + (size_t)bh * SPL * SROW;

    for (int idx = t; idx < CH * HD; idx += 256) {
        int o = idx / HD, dd = idx - o * HD;
        sf[672 + idx] = w[o * CH + h * HD + dd];
    }
    for (int e = t; e < 624; e += 256) {
        float s0 = 0.f, s1 = 0.f, s2 = 0.f, s3 = 0.f;
        #pragma unroll
        for (int sp = 0; sp < SPL; sp += 4) {
            s0 += ld_agent(&base[(size_t)(sp + 0) * SROW + e]);
            s1 += ld_agent(&base[(size_t)(sp + 1) * SROW + e]);
            s2 += ld_agent(&base[(size_t)(sp + 2) * SROW + e]);
            s3 += ld_agent(&base[(size_t)(sp + 3) * SROW + e]);
        }
        sf[e] = (s0 + s1) + (s2 + s3);
    }
    __syncthreads();

    if (t < 2 * HD) {
        float inv = 1.0f / fmaxf(sqrtf(sf[576 + t]), 1e-12f);
        sf[624 + t] = inv;                     // qinv at 624, kinv at 648
    }
    __syncthreads();

    const float sc = scale[h];
    for (int e = t; e < 576; e += 256)
        sf[e] = sf[e] * sf[624 + e / HD] * sf[648 + e % HD] * sc;
    __syncthreads();

    if (t < HD) {   // softmax along j for row t
        float mx = -1e30f;
        for (int j = 0; j < HD; ++j) mx = fmaxf(mx, sf[t * HD + j]);
        float sum = 0.f;
        for (int j = 0; j < HD; ++j) {
            float v = expf(sf[t * HD + j] - mx);
            sf[t * HD + j] = v;
            sum += v;
        }
        float r = 1.0f / sum;
        for (int j = 0; j < HD; ++j) sf[t * HD + j] *= r;
    }
    __syncthreads();

    // Mo[b][o][h*24+j] = (sum_i w[o,h*24+i] * attn[i][j]) * kinv[j]  (bf16)
    // Mo is consumed by the NEXT dispatch (kC): end-of-kernel writeback
    // handles cross-XCD visibility; plain stores are fine here.
    for (int idx = t; idx < CH * HD; idx += 256) {
        int o = idx / HD, j = idx - o * HD;
        float v = 0.f;
        #pragma unroll
        for (int i = 0; i < HD; ++i)
            v = fmaf(sf[672 + o * HD + i], sf[i * HD + j], v);
        Mo[(size_t)b * CH * CH + (size_t)o * CH + h * HD + j] = bf16rne(v * sf[648 + j]);
    }
}

// ---------------------------------------------------------------------------
// Kernel C: out[b][o][n] = sum_c Mo[b][o][c] * in2[b][c][n]  via mfma_32x32x16.
// Block tile O=192 x N=64. Single-shot staging: the ENTIRE 64n x 192c k-tile
// is loaded up-front with 12 float4 loads/thread (1 KB/wave segments, deep
// MLP), ONE barrier, then 36 back-to-back MFMAs. grid (256 nblk, 4 b),
// block 256, 4 blocks/CU.
// ---------------------------------------------------------------------------
#define KCN 64
#define BSTR3 100   // u32 per n-row: 96 data (192 ch as bf16 pairs) + 4 pad

__global__ __launch_bounds__(256, 4) void kC(const float* __restrict__ k,
                                             const unsigned short* __restrict__ Mo,
                                             float* __restrict__ out) {
    __shared__ unsigned int Bt[KCN * BSTR3];   // 25.6 KB

    const int t    = threadIdx.x;
    const int lane = t & 63;
    const int wave = t >> 6;
    const int n31  = lane & 31;
    const int hi   = lane >> 5;
    const int nt   = wave & 1;          // n-tile (x32)
    const int otb  = (wave >> 1) * 3;   // first o-tile (x32) of this wave

    const int nb = blockIdx.x * KCN;
    const int b  = blockIdx.y;

    const float* kb = k + (size_t)b * CH * HW;
    const unsigned short* Mob = Mo + (size_t)b * CH * CH;

    const int np4 = t & 15;   // n-quad: rows np4*4 .. +3
    const int cg4 = t >> 4;   // 0..15: channels cg4*4 .. +3 per 64-ch stage

    // Stage the whole 64 x 192 tile (fp32 -> bf16 pairs), one barrier.
    #pragma unroll
    for (int s = 0; s < 3; ++s) {
        float4 v[4];
        #pragma unroll
        for (int cc = 0; cc < 4; ++cc)
            v[cc] = *(const float4*)(kb + (size_t)(s * 64 + cg4 * 4 + cc) * HW + nb + np4 * 4);
        #pragma unroll
        for (int r = 0; r < 4; ++r) {
            float x0 = (&v[0].x)[r], x1 = (&v[1].x)[r];
            float x2 = (&v[2].x)[r], x3 = (&v[3].x)[r];
            *(uint2*)&Bt[(np4 * 4 + r) * BSTR3 + s * 32 + cg4 * 2] =
                make_uint2(pack2(x0, x1), pack2(x2, x3));
        }
    }
    __syncthreads();

    f32x16 acc[3] = {};
    #pragma unroll
    for (int kc = 0; kc < 12; ++kc) {
        bf16x8 Bf = *(const bf16x8*)&Bt[(nt * 32 + n31) * BSTR3 + kc * 8 + hi * 4];
        #pragma unroll
        for (int oi = 0; oi < 3; ++oi) {
            const unsigned short* ap =
                Mob + (size_t)((otb + oi) * 32 + n31) * CH + kc * 16 + hi * 8;
            bf16x8 Af = *(const bf16x8*)ap;
            acc[oi] = __builtin_amdgcn_mfma_f32_32x32x16_bf16(Af, Bf, acc[oi], 0, 0, 0);
        }
    }

    float* op = out + (size_t)b * CH * HW;
    const int n = nb + nt * 32 + n31;
    #pragma unroll
    for (int oi = 0; oi < 3; ++oi)
        #pragma unroll
        for (int r = 0; r < 16; ++r) {
            int o = (otb + oi) * 32 + (r & 3) + 8 * (r >> 2) + 4 * hi;
            op[(size_t)o * HW + n] = acc[oi][r];
        }
}

extern "C" void kernel_launch(void* const* d_in, const int* in_sizes, int n_in,
                              void* d_out, int out_size, void* d_ws, size_t ws_size,
                              hipStream_t stream) {
    const float* in1   = (const float*)d_in[0];
    const float* in2   = (const float*)d_in[1];
    const float* scale = (const float*)d_in[2];
    const float* projw = (const float*)d_in[3];
    float* ws  = (float*)d_ws;   // needs ~2.9 MB
    float* out = (float*)d_out;
    unsigned short* Mo = (unsigned short*)(ws + OFF_MO);
    unsigned int* cnt  = (unsigned int*)(ws + OFF_CNT);

    // ws is poisoned each iteration by the harness -> zero the 32 semaphores.
    hipMemsetAsync((void*)cnt, 0, 32 * sizeof(unsigned int), stream);
    kA<<<dim3(32, SPL), 256, 0, stream>>>(in1, in2, scale, projw, ws, Mo, cnt);
    kC<<<dim3(HW / KCN, BATCH), 256, 0, stream>>>(in2, Mo, out);
}